// Round 15
// baseline (906.008 us; speedup 1.0000x reference)
//
#include <hip/hip_runtime.h>
#include <hip/hip_fp16.h>
#include <math.h>

#define NN 100000
#define NE 1600000
#define DH 64
#define DO 40
#define NBKT ((NN + 255) >> 8)                 // 391 buckets of 256 rows
#define CAP 5376                                // bucket cap: mean 4096 + 8sigma + pad4
#define P3B 256                                 // blocks in binning pass
#define EPB ((NE + P3B - 1) / P3B)              // 6250 edges per block (exact)
#define X2B (NN * DH / 4 / 256)                 // 6250 x2bf blocks (exact)
#define NN8 ((size_t)NN * 8)                    // elements per feature slice

typedef __attribute__((ext_vector_type(8))) short bf16x8;
typedef __attribute__((ext_vector_type(4))) float f32x4;
typedef __attribute__((ext_vector_type(4))) unsigned short u16x4;

__device__ inline unsigned short f2bf(float f) {   // fp32 -> bf16 RNE
    unsigned u = __float_as_uint(f);
    u = (u + 0x7FFF + ((u >> 16) & 1)) >> 16;
    return (unsigned short)u;
}
__device__ inline float bf2f(unsigned short b) {
    return __uint_as_float((unsigned)b << 16);
}

// ---- pass 1: scatter edges into padded bucket slots (direct reservation) ----
__global__ __launch_bounds__(1024) void bin_scatter_kernel(const int* __restrict__ row,
                                                           const int* __restrict__ col,
                                                           const float* __restrict__ w,
                                                           int* __restrict__ gcur,
                                                           int2* __restrict__ binned) {
    __shared__ int h[NBKT];
    __shared__ int cur[NBKT];
    for (int i = threadIdx.x; i < NBKT; i += 1024) h[i] = 0;
    __syncthreads();
    int base = blockIdx.x * EPB;
    int end = base + EPB; if (end > NE) end = NE;
    for (int e = base + threadIdx.x; e < end; e += 1024)
        atomicAdd(&h[row[e] >> 8], 1);
    __syncthreads();
    for (int i = threadIdx.x; i < NBKT; i += 1024)
        cur[i] = h[i] ? (i * CAP + atomicAdd(&gcur[i], h[i])) : 0;
    __syncthreads();
    for (int e = base + threadIdx.x; e < end; e += 1024) {
        int r = row[e];
        int b = r >> 8;
        int pos = atomicAdd(&cur[b], 1);
        binned[pos] = make_int2(((r & 255) << 17) | col[e], __float_as_int(w[e]));
    }
}

// ---- pass 2: per-bucket finalize. Row ranges padded to multiple of 4;
//      pad slots = 0 (decodes to -0.0 weight -> exact no-op in spmv). ----
__global__ __launch_bounds__(1024) void bfin_kernel(const int* __restrict__ gcur,
                                                    const int2* __restrict__ binned,
                                                    int* __restrict__ ptr,
                                                    int* __restrict__ pend,
                                                    float* __restrict__ dinv,
                                                    unsigned* __restrict__ epack) {
    __shared__ int cnt[256];
    __shared__ float deg[256];
    __shared__ int tmp[256];
    __shared__ int cur[256];
    __shared__ float sdv[256];
    int b = blockIdx.x;
    int s = b * CAP;
    int t = s + gcur[b];
    int tid = threadIdx.x;
    if (tid < 256) { cnt[tid] = 0; deg[tid] = 0.f; }
    __syncthreads();
    for (int i = s + tid; i < t; i += 1024) {
        int2 ep = binned[i];
        int rl = ((unsigned)ep.x) >> 17;
        atomicAdd(&cnt[rl], 1);
        atomicAdd(&deg[rl], __int_as_float(ep.y));
    }
    __syncthreads();
    if (tid < 256) tmp[tid] = (cnt[tid] + 3) & ~3;   // padded counts
    __syncthreads();
    for (int off = 1; off < 256; off <<= 1) {
        int tv = 0;
        if (tid < 256 && tid >= off) tv = tmp[tid - off];
        __syncthreads();
        if (tid < 256) tmp[tid] += tv;
        __syncthreads();
    }
    if (tid < 256) {
        int pc = (cnt[tid] + 3) & ~3;
        int excl = tmp[tid] - pc;
        cur[tid] = excl;
        float d = deg[tid];
        float dv = d > 0.f ? 1.0f / sqrtf(d) : 0.f;
        sdv[tid] = dv;
        int r = (b << 8) + tid;
        if (r < NN) { ptr[r] = s + excl; pend[r] = s + excl + pc; dinv[r] = dv; }
        for (int k = cnt[tid]; k < pc; ++k) epack[s + excl + k] = 0u;  // pad
    }
    __syncthreads();
    for (int i = s + tid; i < t; i += 1024) {
        int2 ep = binned[i];
        int rl = ((unsigned)ep.x) >> 17;
        unsigned c = (unsigned)ep.x & 0x1FFFF;
        int lr = atomicAdd(&cur[rl], 1);
        float tp = __int_as_float(ep.y) * sdv[rl];          // positive partial
        unsigned hb = __half_as_ushort(__float2half(tp));   // bit15 = 0
        epack[s + lr] = (hb << 17) | c;
    }
}

// ---- pass 3: env finalize: w *= dinv[col] (pad/junk slots harmless) ----
__global__ void env_kernel(const float* __restrict__ dinv, unsigned* __restrict__ epack) {
    int e = blockIdx.x * blockDim.x + threadIdx.x;
    if (e < NBKT * CAP) {
        unsigned u = epack[e];
        unsigned c = u & 0x1FFFF;
        float dv = (c < NN) ? dinv[c] : 0.f;
        float wv = __half2float(__ushort_as_half((unsigned short)(u >> 17))) * dv;
        unsigned hb = __half_as_ushort(__float2half(wv));
        epack[e] = (hb << 17) | c;
    }
}

// ---- fused prep: x -> bf16 feature-sliced [8][NN][8]; plus Wt0/1/2 ----
__global__ __launch_bounds__(256) void prep_kernel(const float* __restrict__ x,
                                                   unsigned short* __restrict__ xb,
                                                   const float* __restrict__ W0,
                                                   const float* __restrict__ W1,
                                                   const float* __restrict__ W2,
                                                   unsigned short* __restrict__ Wt0,
                                                   unsigned short* __restrict__ Wt1,
                                                   unsigned short* __restrict__ Wt2) {
    int b = blockIdx.x;
    if (b < X2B) {
        int i = b * 256 + threadIdx.x;      // float4 group: node n, feats 4*f4g..+3
        int n = i >> 4, f4g = i & 15;
        float4 v = ((const float4*)x)[i];
        u16x4 o = {f2bf(v.x), f2bf(v.y), f2bf(v.z), f2bf(v.w)};
        *(u16x4*)(xb + (size_t)(f4g >> 1) * NN8 + (size_t)n * 8 + (f4g & 1) * 4) = o;
    } else {
        int bb = b - X2B;
        int sub = bb / 48;
        int idx = (bb - sub * 48) * 256 + threadIdx.x;
        if (idx >= 64 * 192) return;
        const float* W = sub == 0 ? W0 : (sub == 1 ? W1 : W2);
        unsigned short* Wt = sub == 0 ? Wt0 : (sub == 1 ? Wt1 : Wt2);
        int SW = sub == 2 ? 40 : 64;
        int n = idx / 192, k = idx - n * 192;
        int j = k >> 6, kin = k & 63;
        float v = 0.f;
        if (n < SW) {
            if (j == 0)      v = W[kin * SW + n] - W[2 * 64 * SW + kin * SW + n];
            else if (j == 1) v = W[64 * SW + kin * SW + n];
            else             v = 2.f * W[2 * 64 * SW + kin * SW + n];
        }
        Wt[n * 192 + k] = f2bf(v);
    }
}

// ---- slice SpMV: block handles feature slice fs = blockIdx&7 (-> XCD fs via
//      round-robin dispatch; perf heuristic only). Per-XCD gather working set
//      = NN*16B = 1.6MB -> L2-resident. Wave = 8 rows x (4 lanes x 2 edges).
//      Register accumulation; NT loads on the record stream. ----
__global__ __launch_bounds__(256) void spmv_s_kernel(const int* __restrict__ ptr,
                                                     const int* __restrict__ pend,
                                                     const unsigned* __restrict__ epack,
                                                     const unsigned short* __restrict__ h,
                                                     unsigned short* __restrict__ y) {
    int fs = blockIdx.x & 7;
    int tile = blockIdx.x >> 3;
    int tid = threadIdx.x;
    int lane = tid & 63;
    int g = lane >> 3;                  // sub-row 0..7
    int k = lane & 7;
    int half = k >> 2;                  // edge parity within pair
    int kk = k & 3;                     // feature pair (feats 2kk, 2kk+1)
    int r = tile * 32 + (tid >> 6) * 8 + g;
    const unsigned short* hs = h + (size_t)fs * NN8;
    int s = 0, e = 0;
    if (r < NN) { s = ptr[r]; e = pend[r]; }
    float a0 = 0.f, a1 = 0.f, b0_ = 0.f, b1_ = 0.f;
#define DEC(u) __half2float(__ushort_as_half((unsigned short)(0x8000u | ((u) >> 17))))
    int i = s;
    for (; i + 8 <= e; i += 8) {
        unsigned ra = __builtin_nontemporal_load(&epack[i + half]);
        unsigned rb = __builtin_nontemporal_load(&epack[i + 2 + half]);
        unsigned rc = __builtin_nontemporal_load(&epack[i + 4 + half]);
        unsigned rd = __builtin_nontemporal_load(&epack[i + 6 + half]);
        ushort2 ha = *(const ushort2*)(hs + (size_t)(ra & 0x1FFFF) * 8 + kk * 2);
        ushort2 hb = *(const ushort2*)(hs + (size_t)(rb & 0x1FFFF) * 8 + kk * 2);
        ushort2 hc = *(const ushort2*)(hs + (size_t)(rc & 0x1FFFF) * 8 + kk * 2);
        ushort2 hd = *(const ushort2*)(hs + (size_t)(rd & 0x1FFFF) * 8 + kk * 2);
        float wa = DEC(ra), wb = DEC(rb), wc = DEC(rc), wd = DEC(rd);
        a0 = fmaf(wa, bf2f(ha.x), a0); a1 = fmaf(wa, bf2f(ha.y), a1);
        b0_ = fmaf(wb, bf2f(hb.x), b0_); b1_ = fmaf(wb, bf2f(hb.y), b1_);
        a0 = fmaf(wc, bf2f(hc.x), a0); a1 = fmaf(wc, bf2f(hc.y), a1);
        b0_ = fmaf(wd, bf2f(hd.x), b0_); b1_ = fmaf(wd, bf2f(hd.y), b1_);
    }
    for (; i < e; i += 2) {
        unsigned ra = __builtin_nontemporal_load(&epack[i + half]);
        ushort2 ha = *(const ushort2*)(hs + (size_t)(ra & 0x1FFFF) * 8 + kk * 2);
        float wa = DEC(ra);
        a0 = fmaf(wa, bf2f(ha.x), a0); a1 = fmaf(wa, bf2f(ha.y), a1);
    }
#undef DEC
    float f0 = a0 + b0_, f1 = a1 + b1_;
    f0 += __shfl_xor(f0, 4);            // combine edge-parity halves
    f1 += __shfl_xor(f1, 4);
    if (r < NN && half == 0) {
        ushort2 o; o.x = f2bf(f0); o.y = f2bf(f1);
        *(ushort2*)(y + (size_t)fs * NN8 + (size_t)r * 8 + kk * 2) = o;
    }
}

// ---- MFMA GEMM on sliced layout: A-frag = one full 8-feat slice row ----
template<int SW, int NT, int OBF>
__global__ __launch_bounds__(256)
void gemm3_mfma_kernel(const unsigned short* __restrict__ h,
                       const unsigned short* __restrict__ y1,
                       const unsigned short* __restrict__ y2,
                       const unsigned short* __restrict__ Wt,
                       const float* __restrict__ bg, void* __restrict__ outg) {
    int tid = threadIdx.x;
    int w = tid >> 6, l = tid & 63;
    int m = l & 15, kg = l >> 4;
    int node = blockIdx.x * 64 + w * 16 + m;
    int nclamp = node < NN ? node : NN - 1;

    f32x4 acc[NT];
    #pragma unroll
    for (int t = 0; t < NT; ++t) acc[t] = (f32x4){0.f, 0.f, 0.f, 0.f};

    #pragma unroll
    for (int ks = 0; ks < 6; ++ks) {
        const unsigned short* src = (ks < 2) ? h : (ks < 4 ? y1 : y2);
        int kin = (ks & 1) * 32 + kg * 8;
        bf16x8 af = *(const bf16x8*)(src + (size_t)(kin >> 3) * NN8 + (size_t)nclamp * 8);
        #pragma unroll
        for (int t = 0; t < NT; ++t) {
            const bf16x8* pb = (const bf16x8*)(Wt + ((size_t)(t * 16 + m) * 192 + ks * 32 + kg * 8));
            acc[t] = __builtin_amdgcn_mfma_f32_16x16x32_bf16(af, *pb, acc[t], 0, 0, 0);
        }
    }

    int orow = blockIdx.x * 64 + w * 16 + kg * 4;   // + r
    #pragma unroll
    for (int t = 0; t < NT; ++t) {
        int oc = t * 16 + m;
        float bias = (oc < SW) ? bg[oc] : 0.f;
        #pragma unroll
        for (int r = 0; r < 4; ++r) {
            int nd = orow + r;
            if (nd < NN && oc < SW) {
                float v = fmaxf(acc[t][r] + bias, 0.f);
                if (OBF) ((unsigned short*)outg)[(size_t)(oc >> 3) * NN8 + (size_t)nd * 8 + (oc & 7)] = f2bf(v);
                else     ((float*)outg)[(size_t)nd * SW + oc] = v;
            }
        }
    }
}

// ---- final GEMM with fused relu + log_softmax (SW=40, 3 col-tiles) ----
__global__ __launch_bounds__(256)
void gemm3_lsm_kernel(const unsigned short* __restrict__ h,
                      const unsigned short* __restrict__ y1,
                      const unsigned short* __restrict__ y2,
                      const unsigned short* __restrict__ Wt,
                      const float* __restrict__ bg, float* __restrict__ outg) {
    const int SW = 40;
    int tid = threadIdx.x;
    int w = tid >> 6, l = tid & 63;
    int m = l & 15, kg = l >> 4;
    int node = blockIdx.x * 64 + w * 16 + m;
    int nclamp = node < NN ? node : NN - 1;

    f32x4 acc[3];
    #pragma unroll
    for (int t = 0; t < 3; ++t) acc[t] = (f32x4){0.f, 0.f, 0.f, 0.f};

    #pragma unroll
    for (int ks = 0; ks < 6; ++ks) {
        const unsigned short* src = (ks < 2) ? h : (ks < 4 ? y1 : y2);
        int kin = (ks & 1) * 32 + kg * 8;
        bf16x8 af = *(const bf16x8*)(src + (size_t)(kin >> 3) * NN8 + (size_t)nclamp * 8);
        #pragma unroll
        for (int t = 0; t < 3; ++t) {
            const bf16x8* pb = (const bf16x8*)(Wt + ((size_t)(t * 16 + m) * 192 + ks * 32 + kg * 8));
            acc[t] = __builtin_amdgcn_mfma_f32_16x16x32_bf16(af, *pb, acc[t], 0, 0, 0);
        }
    }

    int orow = blockIdx.x * 64 + w * 16 + kg * 4;   // + r
    float v[3][4];
    #pragma unroll
    for (int t = 0; t < 3; ++t) {
        int oc = t * 16 + m;
        float bias = (oc < SW) ? bg[oc] : 0.f;
        #pragma unroll
        for (int r = 0; r < 4; ++r) v[t][r] = fmaxf(acc[t][r] + bias, 0.f);
    }
    bool ok2 = (m < 8);   // t=2 -> oc=32+m valid iff m<8
    #pragma unroll
    for (int r = 0; r < 4; ++r) {
        float mx = fmaxf(v[0][r], v[1][r]);
        if (ok2) mx = fmaxf(mx, v[2][r]);
        #pragma unroll
        for (int off = 1; off < 16; off <<= 1) mx = fmaxf(mx, __shfl_xor(mx, off));
        float sm = __expf(v[0][r] - mx) + __expf(v[1][r] - mx);
        if (ok2) sm += __expf(v[2][r] - mx);
        #pragma unroll
        for (int off = 1; off < 16; off <<= 1) sm += __shfl_xor(sm, off);
        float lse = mx + __logf(sm);
        int nd = orow + r;
        if (nd < NN) {
            outg[(size_t)nd * SW + m] = v[0][r] - lse;
            outg[(size_t)nd * SW + 16 + m] = v[1][r] - lse;
            if (ok2) outg[(size_t)nd * SW + 32 + m] = v[2][r] - lse;
        }
    }
}

extern "C" void kernel_launch(void* const* d_in, const int* in_sizes, int n_in,
                              void* d_out, int out_size, void* d_ws, size_t ws_size,
                              hipStream_t stream) {
    const float* x  = (const float*)d_in[0];
    const int*   ei = (const int*)d_in[1];
    const float* ea = (const float*)d_in[2];
    const float* W0 = (const float*)d_in[3];
    const float* b0 = (const float*)d_in[4];
    const float* W1 = (const float*)d_in[5];
    const float* b1 = (const float*)d_in[6];
    const float* W2 = (const float*)d_in[7];
    const float* b2 = (const float*)d_in[8];
    float* out = (float*)d_out;

    const int* row = ei;
    const int* col = ei + NE;

    const size_t HB2 = (size_t)NN * DH * 2;     // bf16 node-feature buffer
    char* p = (char*)d_ws;
    int*      ptr    = (int*)p;      p += (size_t)(NN + 4) * 4;
    int*      pendp  = (int*)p;      p += (size_t)(NN + 4) * 4;
    unsigned* epack  = (unsigned*)p; p += (size_t)NBKT * CAP * 4;
    int2*     binned = (int2*)p;     p += (size_t)NBKT * CAP * 8;
    float*    dinv   = (float*)p;    p += (size_t)NN * 4;
    int*      gcur   = (int*)p;      p += (size_t)(NBKT + 4) * 4;
    unsigned short* xb  = (unsigned short*)p; p += HB2;
    unsigned short* y1b = (unsigned short*)p; p += HB2;
    unsigned short* y2b = (unsigned short*)p; p += HB2;
    unsigned short* hAb = (unsigned short*)p; p += HB2;
    unsigned short* hBb = (unsigned short*)p; p += HB2;
    unsigned short* Wt0 = (unsigned short*)p; p += (size_t)64 * 192 * 2;
    unsigned short* Wt1 = (unsigned short*)p; p += (size_t)64 * 192 * 2;
    unsigned short* Wt2 = (unsigned short*)p; p += (size_t)64 * 192 * 2;

    // ---- fused prep: x->bf16 (sliced) + weight transforms ----
    prep_kernel<<<X2B + 144, 256, 0, stream>>>(x, xb, W0, W1, W2, Wt0, Wt1, Wt2);

    // ---- padded-bucket build: scatter -> finalize -> env ----
    hipMemsetAsync(gcur, 0, (size_t)NBKT * 4, stream);
    bin_scatter_kernel<<<P3B, 1024, 0, stream>>>(row, col, ea, gcur, binned);
    bfin_kernel<<<NBKT, 1024, 0, stream>>>(gcur, binned, ptr, pendp, dinv, epack);
    env_kernel<<<(NBKT * CAP + 255) / 256, 256, 0, stream>>>(dinv, epack);

    const int SPMV_GRID = ((NN + 31) / 32) * 8;   // 3125 row-tiles x 8 slices
    const int GEMM_GRID = (NN + 63) / 64;

    // ---- layer 0 (h = xb) ----
    spmv_s_kernel<<<SPMV_GRID, 256, 0, stream>>>(ptr, pendp, epack, xb, y1b);
    spmv_s_kernel<<<SPMV_GRID, 256, 0, stream>>>(ptr, pendp, epack, y1b, y2b);
    gemm3_mfma_kernel<64, 4, 1><<<GEMM_GRID, 256, 0, stream>>>(xb, y1b, y2b, Wt0, b0, hAb);

    // ---- layer 1 (h = hAb) ----
    spmv_s_kernel<<<SPMV_GRID, 256, 0, stream>>>(ptr, pendp, epack, hAb, y1b);
    spmv_s_kernel<<<SPMV_GRID, 256, 0, stream>>>(ptr, pendp, epack, y1b, y2b);
    gemm3_mfma_kernel<64, 4, 1><<<GEMM_GRID, 256, 0, stream>>>(hAb, y1b, y2b, Wt1, b1, hBb);

    // ---- layer 2 (h = hBb) -> fused gemm+log_softmax into d_out ----
    spmv_s_kernel<<<SPMV_GRID, 256, 0, stream>>>(ptr, pendp, epack, hBb, y1b);
    spmv_s_kernel<<<SPMV_GRID, 256, 0, stream>>>(ptr, pendp, epack, y1b, y2b);
    gemm3_lsm_kernel<<<GEMM_GRID, 256, 0, stream>>>(hBb, y1b, y2b, Wt2, b2, out);
}

// Round 16
// 431.073 us; speedup vs baseline: 2.1018x; 2.1018x over previous
//
#include <hip/hip_runtime.h>
#include <hip/hip_fp16.h>
#include <math.h>

#define NN 100000
#define NE 1600000
#define DH 64
#define DO 40
#define NBKT ((NN + 255) >> 8)                 // 391 buckets of 256 rows
#define CAP 4608                                // bucket capacity: mean 4096 + 8 sigma
#define P3B 256                                 // blocks in binning pass
#define EPB ((NE + P3B - 1) / P3B)              // 6250 edges per block (exact)
#define X2B (NN * DH / 4 / 256)                 // 6250 x2bf blocks (exact)

typedef __attribute__((ext_vector_type(8))) short bf16x8;
typedef __attribute__((ext_vector_type(4))) float f32x4;
typedef __attribute__((ext_vector_type(4))) unsigned short u16x4;

__device__ inline unsigned short f2bf(float f) {   // fp32 -> bf16 RNE
    unsigned u = __float_as_uint(f);
    u = (u + 0x7FFF + ((u >> 16) & 1)) >> 16;
    return (unsigned short)u;
}
__device__ inline float bf2f(unsigned short b) {
    return __uint_as_float((unsigned)b << 16);
}

// ---- pass 1: scatter edges into padded bucket slots (direct reservation,
//      no precount pass). binned[pos] = ((row&255)<<17 | col, w_f32) ----
__global__ __launch_bounds__(1024) void bin_scatter_kernel(const int* __restrict__ row,
                                                           const int* __restrict__ col,
                                                           const float* __restrict__ w,
                                                           int* __restrict__ gcur,
                                                           int2* __restrict__ binned) {
    __shared__ int h[NBKT];
    __shared__ int cur[NBKT];
    for (int i = threadIdx.x; i < NBKT; i += 1024) h[i] = 0;
    __syncthreads();
    int base = blockIdx.x * EPB;
    int end = base + EPB; if (end > NE) end = NE;
    for (int e = base + threadIdx.x; e < end; e += 1024)
        atomicAdd(&h[row[e] >> 8], 1);
    __syncthreads();
    for (int i = threadIdx.x; i < NBKT; i += 1024)
        cur[i] = h[i] ? (i * CAP + atomicAdd(&gcur[i], h[i])) : 0;
    __syncthreads();
    for (int e = base + threadIdx.x; e < end; e += 1024) {
        int r = row[e];
        int b = r >> 8;
        int pos = atomicAdd(&cur[b], 1);
        binned[pos] = make_int2(((r & 255) << 17) | col[e], __float_as_int(w[e]));
    }
}

// ---- pass 2: per-bucket finalize: deg/dinv, per-row slot ranges (ptr/pend),
//      emit u32 edge record: (half15(w*dinv_row) << 17) | col ----
__global__ __launch_bounds__(1024) void bfin_kernel(const int* __restrict__ gcur,
                                                    const int2* __restrict__ binned,
                                                    int* __restrict__ ptr,
                                                    int* __restrict__ pend,
                                                    float* __restrict__ dinv,
                                                    unsigned* __restrict__ epack) {
    __shared__ int cnt[256];
    __shared__ float deg[256];
    __shared__ int tmp[256];
    __shared__ int cur[256];
    __shared__ float sdv[256];
    int b = blockIdx.x;
    int s = b * CAP;
    int t = s + gcur[b];
    int tid = threadIdx.x;
    if (tid < 256) { cnt[tid] = 0; deg[tid] = 0.f; }
    __syncthreads();
    for (int i = s + tid; i < t; i += 1024) {
        int2 ep = binned[i];
        int rl = ((unsigned)ep.x) >> 17;
        atomicAdd(&cnt[rl], 1);
        atomicAdd(&deg[rl], __int_as_float(ep.y));
    }
    __syncthreads();
    if (tid < 256) tmp[tid] = cnt[tid];
    __syncthreads();
    for (int off = 1; off < 256; off <<= 1) {
        int tv = 0;
        if (tid < 256 && tid >= off) tv = tmp[tid - off];
        __syncthreads();
        if (tid < 256) tmp[tid] += tv;
        __syncthreads();
    }
    if (tid < 256) {
        int excl = tmp[tid] - cnt[tid];
        cur[tid] = excl;
        float d = deg[tid];
        float dv = d > 0.f ? 1.0f / sqrtf(d) : 0.f;
        sdv[tid] = dv;
        int r = (b << 8) + tid;
        if (r < NN) { ptr[r] = s + excl; pend[r] = s + excl + cnt[tid]; dinv[r] = dv; }
    }
    __syncthreads();
    for (int i = s + tid; i < t; i += 1024) {
        int2 ep = binned[i];
        int rl = ((unsigned)ep.x) >> 17;
        unsigned c = (unsigned)ep.x & 0x1FFFF;
        int lr = atomicAdd(&cur[rl], 1);
        float tp = __int_as_float(ep.y) * sdv[rl];          // positive partial
        unsigned hb = __half_as_ushort(__float2half(tp));   // bit15 = 0
        epack[s + lr] = (hb << 17) | c;
    }
}

// ---- pass 3: env finalize: w *= dinv[col] (u32 RMW; gap slots harmless) ----
__global__ void env_kernel(const float* __restrict__ dinv, unsigned* __restrict__ epack) {
    int e = blockIdx.x * blockDim.x + threadIdx.x;
    if (e < NBKT * CAP) {
        unsigned u = epack[e];
        unsigned c = u & 0x1FFFF;
        float dv = (c < NN) ? dinv[c] : 0.f;
        float wv = __half2float(__ushort_as_half((unsigned short)(u >> 17))) * dv;
        unsigned hb = __half_as_ushort(__float2half(wv));
        epack[e] = (hb << 17) | c;
    }
}

// ---- fused prep: blocks [0,X2B) convert x->bf16; rest build Wt0/1/2 ----
// Wt[n][192] bf16; j=0: W[0]-W[2]; j=1: W[1]; j=2: 2*W[2]
__global__ __launch_bounds__(256) void prep_kernel(const float* __restrict__ x,
                                                   unsigned short* __restrict__ xb,
                                                   const float* __restrict__ W0,
                                                   const float* __restrict__ W1,
                                                   const float* __restrict__ W2,
                                                   unsigned short* __restrict__ Wt0,
                                                   unsigned short* __restrict__ Wt1,
                                                   unsigned short* __restrict__ Wt2) {
    int b = blockIdx.x;
    if (b < X2B) {
        int i = b * 256 + threadIdx.x;
        float4 v = ((const float4*)x)[i];
        u16x4 o = {f2bf(v.x), f2bf(v.y), f2bf(v.z), f2bf(v.w)};
        ((u16x4*)xb)[i] = o;
    } else {
        int bb = b - X2B;
        int sub = bb / 48;
        int idx = (bb - sub * 48) * 256 + threadIdx.x;
        if (idx >= 64 * 192) return;
        const float* W = sub == 0 ? W0 : (sub == 1 ? W1 : W2);
        unsigned short* Wt = sub == 0 ? Wt0 : (sub == 1 ? Wt1 : Wt2);
        int SW = sub == 2 ? 40 : 64;
        int n = idx / 192, k = idx - n * 192;
        int j = k >> 6, kin = k & 63;
        float v = 0.f;
        if (n < SW) {
            if (j == 0)      v = W[kin * SW + n] - W[2 * 64 * SW + kin * SW + n];
            else if (j == 1) v = W[64 * SW + kin * SW + n];
            else             v = 2.f * W[2 * 64 * SW + kin * SW + n];
        }
        Wt[n * 192 + k] = f2bf(v);
    }
}

// ---- CSR SpMV: one wave/row; 4B edge records scalar-loaded (wave-uniform),
//      SALU decode, sign restored via 0x8000 OR; 16-deep gather ILP ----
__global__ __launch_bounds__(256) void spmv_csr_kernel(const int* __restrict__ ptr,
                                                       const int* __restrict__ pend,
                                                       const unsigned* __restrict__ epack,
                                                       const unsigned short* __restrict__ h,
                                                       unsigned short* __restrict__ y) {
    int g = blockIdx.x * blockDim.x + threadIdx.x;
    int r = __builtin_amdgcn_readfirstlane(g >> 6);
    int lane = threadIdx.x & 63;
    if (r >= NN) return;
    int s = ptr[r], t = pend[r];
    float a0 = 0.f, a1 = 0.f, a2 = 0.f, a3 = 0.f;
    float a4 = 0.f, a5 = 0.f, a6 = 0.f, a7 = 0.f;
#define DEC(u) __half2float(__ushort_as_half((unsigned short)(0x8000u | ((u) >> 17))))
    int i = s;
    for (; i + 16 <= t; i += 16) {
        unsigned u0 = epack[i];      unsigned u1 = epack[i + 1];
        unsigned u2 = epack[i + 2];  unsigned u3 = epack[i + 3];
        unsigned u4 = epack[i + 4];  unsigned u5 = epack[i + 5];
        unsigned u6 = epack[i + 6];  unsigned u7 = epack[i + 7];
        unsigned u8 = epack[i + 8];  unsigned u9 = epack[i + 9];
        unsigned uA = epack[i + 10]; unsigned uB = epack[i + 11];
        unsigned uC = epack[i + 12]; unsigned uD = epack[i + 13];
        unsigned uE = epack[i + 14]; unsigned uF = epack[i + 15];
        unsigned short h0 = h[(size_t)(u0 & 0x1FFFF) * DH + lane];
        unsigned short h1 = h[(size_t)(u1 & 0x1FFFF) * DH + lane];
        unsigned short h2 = h[(size_t)(u2 & 0x1FFFF) * DH + lane];
        unsigned short h3 = h[(size_t)(u3 & 0x1FFFF) * DH + lane];
        unsigned short h4 = h[(size_t)(u4 & 0x1FFFF) * DH + lane];
        unsigned short h5 = h[(size_t)(u5 & 0x1FFFF) * DH + lane];
        unsigned short h6 = h[(size_t)(u6 & 0x1FFFF) * DH + lane];
        unsigned short h7 = h[(size_t)(u7 & 0x1FFFF) * DH + lane];
        unsigned short h8 = h[(size_t)(u8 & 0x1FFFF) * DH + lane];
        unsigned short h9 = h[(size_t)(u9 & 0x1FFFF) * DH + lane];
        unsigned short hA = h[(size_t)(uA & 0x1FFFF) * DH + lane];
        unsigned short hB = h[(size_t)(uB & 0x1FFFF) * DH + lane];
        unsigned short hC = h[(size_t)(uC & 0x1FFFF) * DH + lane];
        unsigned short hD = h[(size_t)(uD & 0x1FFFF) * DH + lane];
        unsigned short hE = h[(size_t)(uE & 0x1FFFF) * DH + lane];
        unsigned short hF = h[(size_t)(uF & 0x1FFFF) * DH + lane];
        a0 = fmaf(DEC(u0), bf2f(h0), a0); a1 = fmaf(DEC(u1), bf2f(h1), a1);
        a2 = fmaf(DEC(u2), bf2f(h2), a2); a3 = fmaf(DEC(u3), bf2f(h3), a3);
        a4 = fmaf(DEC(u4), bf2f(h4), a4); a5 = fmaf(DEC(u5), bf2f(h5), a5);
        a6 = fmaf(DEC(u6), bf2f(h6), a6); a7 = fmaf(DEC(u7), bf2f(h7), a7);
        a0 = fmaf(DEC(u8), bf2f(h8), a0); a1 = fmaf(DEC(u9), bf2f(h9), a1);
        a2 = fmaf(DEC(uA), bf2f(hA), a2); a3 = fmaf(DEC(uB), bf2f(hB), a3);
        a4 = fmaf(DEC(uC), bf2f(hC), a4); a5 = fmaf(DEC(uD), bf2f(hD), a5);
        a6 = fmaf(DEC(uE), bf2f(hE), a6); a7 = fmaf(DEC(uF), bf2f(hF), a7);
    }
    for (; i + 4 <= t; i += 4) {
        unsigned u0 = epack[i];     unsigned u1 = epack[i + 1];
        unsigned u2 = epack[i + 2]; unsigned u3 = epack[i + 3];
        unsigned short h0 = h[(size_t)(u0 & 0x1FFFF) * DH + lane];
        unsigned short h1 = h[(size_t)(u1 & 0x1FFFF) * DH + lane];
        unsigned short h2 = h[(size_t)(u2 & 0x1FFFF) * DH + lane];
        unsigned short h3 = h[(size_t)(u3 & 0x1FFFF) * DH + lane];
        a0 = fmaf(DEC(u0), bf2f(h0), a0); a1 = fmaf(DEC(u1), bf2f(h1), a1);
        a2 = fmaf(DEC(u2), bf2f(h2), a2); a3 = fmaf(DEC(u3), bf2f(h3), a3);
    }
    for (; i < t; ++i) {
        unsigned u = epack[i];
        a0 = fmaf(DEC(u), bf2f(h[(size_t)(u & 0x1FFFF) * DH + lane]), a0);
    }
#undef DEC
    float res = ((a0 + a1) + (a2 + a3)) + ((a4 + a5) + (a6 + a7));
    y[(size_t)r * DH + lane] = f2bf(res);
}

// ---- MFMA GEMM: out = relu(h@Wt_j0 + y1@Wt_j1 + y2@Wt_j2 + b) ----
template<int SW, int NT, int OBF>
__global__ __launch_bounds__(256)
void gemm3_mfma_kernel(const unsigned short* __restrict__ h,
                       const unsigned short* __restrict__ y1,
                       const unsigned short* __restrict__ y2,
                       const unsigned short* __restrict__ Wt,
                       const float* __restrict__ bg, void* __restrict__ outg) {
    int tid = threadIdx.x;
    int w = tid >> 6, l = tid & 63;
    int m = l & 15, kg = l >> 4;
    int node = blockIdx.x * 64 + w * 16 + m;
    int nclamp = node < NN ? node : NN - 1;

    f32x4 acc[NT];
    #pragma unroll
    for (int t = 0; t < NT; ++t) acc[t] = (f32x4){0.f, 0.f, 0.f, 0.f};

    #pragma unroll
    for (int ks = 0; ks < 6; ++ks) {
        const unsigned short* src = (ks < 2) ? h : (ks < 4 ? y1 : y2);
        int kin = (ks & 1) * 32 + kg * 8;
        bf16x8 af = *(const bf16x8*)(src + (size_t)nclamp * DH + kin);
        #pragma unroll
        for (int t = 0; t < NT; ++t) {
            const bf16x8* pb = (const bf16x8*)(Wt + ((size_t)(t * 16 + m) * 192 + ks * 32 + kg * 8));
            acc[t] = __builtin_amdgcn_mfma_f32_16x16x32_bf16(af, *pb, acc[t], 0, 0, 0);
        }
    }

    int orow = blockIdx.x * 64 + w * 16 + kg * 4;   // + r
    #pragma unroll
    for (int t = 0; t < NT; ++t) {
        int oc = t * 16 + m;
        float bias = (oc < SW) ? bg[oc] : 0.f;
        #pragma unroll
        for (int r = 0; r < 4; ++r) {
            int nd = orow + r;
            if (nd < NN && oc < SW) {
                float v = fmaxf(acc[t][r] + bias, 0.f);
                if (OBF) ((unsigned short*)outg)[(size_t)nd * SW + oc] = f2bf(v);
                else     ((float*)outg)[(size_t)nd * SW + oc] = v;
            }
        }
    }
}

// ---- final GEMM with fused relu + log_softmax (SW=40, 3 col-tiles) ----
__global__ __launch_bounds__(256)
void gemm3_lsm_kernel(const unsigned short* __restrict__ h,
                      const unsigned short* __restrict__ y1,
                      const unsigned short* __restrict__ y2,
                      const unsigned short* __restrict__ Wt,
                      const float* __restrict__ bg, float* __restrict__ outg) {
    const int SW = 40;
    int tid = threadIdx.x;
    int w = tid >> 6, l = tid & 63;
    int m = l & 15, kg = l >> 4;
    int node = blockIdx.x * 64 + w * 16 + m;
    int nclamp = node < NN ? node : NN - 1;

    f32x4 acc[3];
    #pragma unroll
    for (int t = 0; t < 3; ++t) acc[t] = (f32x4){0.f, 0.f, 0.f, 0.f};

    #pragma unroll
    for (int ks = 0; ks < 6; ++ks) {
        const unsigned short* src = (ks < 2) ? h : (ks < 4 ? y1 : y2);
        int kin = (ks & 1) * 32 + kg * 8;
        bf16x8 af = *(const bf16x8*)(src + (size_t)nclamp * DH + kin);
        #pragma unroll
        for (int t = 0; t < 3; ++t) {
            const bf16x8* pb = (const bf16x8*)(Wt + ((size_t)(t * 16 + m) * 192 + ks * 32 + kg * 8));
            acc[t] = __builtin_amdgcn_mfma_f32_16x16x32_bf16(af, *pb, acc[t], 0, 0, 0);
        }
    }

    int orow = blockIdx.x * 64 + w * 16 + kg * 4;   // + r
    float v[3][4];
    #pragma unroll
    for (int t = 0; t < 3; ++t) {
        int oc = t * 16 + m;
        float bias = (oc < SW) ? bg[oc] : 0.f;
        #pragma unroll
        for (int r = 0; r < 4; ++r) v[t][r] = fmaxf(acc[t][r] + bias, 0.f);
    }
    bool ok2 = (m < 8);   // t=2 -> oc=32+m valid iff m<8
    #pragma unroll
    for (int r = 0; r < 4; ++r) {
        float mx = fmaxf(v[0][r], v[1][r]);
        if (ok2) mx = fmaxf(mx, v[2][r]);
        #pragma unroll
        for (int off = 1; off < 16; off <<= 1) mx = fmaxf(mx, __shfl_xor(mx, off));
        float sm = __expf(v[0][r] - mx) + __expf(v[1][r] - mx);
        if (ok2) sm += __expf(v[2][r] - mx);
        #pragma unroll
        for (int off = 1; off < 16; off <<= 1) sm += __shfl_xor(sm, off);
        float lse = mx + __logf(sm);
        int nd = orow + r;
        if (nd < NN) {
            outg[(size_t)nd * SW + m] = v[0][r] - lse;
            outg[(size_t)nd * SW + 16 + m] = v[1][r] - lse;
            if (ok2) outg[(size_t)nd * SW + 32 + m] = v[2][r] - lse;
        }
    }
}

extern "C" void kernel_launch(void* const* d_in, const int* in_sizes, int n_in,
                              void* d_out, int out_size, void* d_ws, size_t ws_size,
                              hipStream_t stream) {
    const float* x  = (const float*)d_in[0];
    const int*   ei = (const int*)d_in[1];
    const float* ea = (const float*)d_in[2];
    const float* W0 = (const float*)d_in[3];
    const float* b0 = (const float*)d_in[4];
    const float* W1 = (const float*)d_in[5];
    const float* b1 = (const float*)d_in[6];
    const float* W2 = (const float*)d_in[7];
    const float* b2 = (const float*)d_in[8];
    float* out = (float*)d_out;

    const int* row = ei;
    const int* col = ei + NE;

    const size_t HB2 = (size_t)NN * DH * 2;     // bf16 node-feature buffer
    char* p = (char*)d_ws;
    int*      ptr    = (int*)p;      p += (size_t)(NN + 4) * 4;
    int*      pendp  = (int*)p;      p += (size_t)(NN + 4) * 4;
    unsigned* epack  = (unsigned*)p; p += (size_t)NBKT * CAP * 4;
    int2*     binned = (int2*)p;     p += (size_t)NBKT * CAP * 8;
    float*    dinv   = (float*)p;    p += (size_t)NN * 4;
    int*      gcur   = (int*)p;      p += (size_t)(NBKT + 4) * 4;
    unsigned short* xb  = (unsigned short*)p; p += HB2;
    unsigned short* y1b = (unsigned short*)p; p += HB2;
    unsigned short* y2b = (unsigned short*)p; p += HB2;
    unsigned short* hAb = (unsigned short*)p; p += HB2;
    unsigned short* hBb = (unsigned short*)p; p += HB2;
    unsigned short* Wt0 = (unsigned short*)p; p += (size_t)64 * 192 * 2;
    unsigned short* Wt1 = (unsigned short*)p; p += (size_t)64 * 192 * 2;
    unsigned short* Wt2 = (unsigned short*)p; p += (size_t)64 * 192 * 2;

    // ---- fused prep: x->bf16 + weight transforms ----
    prep_kernel<<<X2B + 144, 256, 0, stream>>>(x, xb, W0, W1, W2, Wt0, Wt1, Wt2);

    // ---- padded-bucket build: scatter -> finalize -> env (no precount) ----
    hipMemsetAsync(gcur, 0, (size_t)NBKT * 4, stream);
    bin_scatter_kernel<<<P3B, 1024, 0, stream>>>(row, col, ea, gcur, binned);
    bfin_kernel<<<NBKT, 1024, 0, stream>>>(gcur, binned, ptr, pendp, dinv, epack);
    env_kernel<<<(NBKT * CAP + 255) / 256, 256, 0, stream>>>(dinv, epack);

    const int SPMV_GRID = (NN * 64 + 255) / 256;
    const int GEMM_GRID = (NN + 63) / 64;

    // ---- layer 0 (h = xb) ----
    spmv_csr_kernel<<<SPMV_GRID, 256, 0, stream>>>(ptr, pendp, epack, xb, y1b);
    spmv_csr_kernel<<<SPMV_GRID, 256, 0, stream>>>(ptr, pendp, epack, y1b, y2b);
    gemm3_mfma_kernel<64, 4, 1><<<GEMM_GRID, 256, 0, stream>>>(xb, y1b, y2b, Wt0, b0, hAb);

    // ---- layer 1 (h = hAb) ----
    spmv_csr_kernel<<<SPMV_GRID, 256, 0, stream>>>(ptr, pendp, epack, hAb, y1b);
    spmv_csr_kernel<<<SPMV_GRID, 256, 0, stream>>>(ptr, pendp, epack, y1b, y2b);
    gemm3_mfma_kernel<64, 4, 1><<<GEMM_GRID, 256, 0, stream>>>(hAb, y1b, y2b, Wt1, b1, hBb);

    // ---- layer 2 (h = hBb) -> fused gemm+log_softmax into d_out ----
    spmv_csr_kernel<<<SPMV_GRID, 256, 0, stream>>>(ptr, pendp, epack, hBb, y1b);
    spmv_csr_kernel<<<SPMV_GRID, 256, 0, stream>>>(ptr, pendp, epack, y1b, y2b);
    gemm3_lsm_kernel<<<GEMM_GRID, 256, 0, stream>>>(hBb, y1b, y2b, Wt2, b2, out);
}